// Round 1
// baseline (178.377 us; speedup 1.0000x reference)
//
#include <hip/hip_runtime.h>
#include <math.h>

#define N_POINTS 50000
#define MAX_DEG 16
#define BATCH 32
#define ROW (BATCH * 3)   // 96 floats = 384 bytes per delta row

// ---------------------------------------------------------------------------
// Kernel 1: delta[n][b][c] = predict[b][n][c] - gt[b][n][c], transposed layout
// [N_POINTS+1][96] so that kernel 2's gather of one neighbour row is 384
// contiguous bytes across a 32-lane half-wave (lane = batch). Row N is the
// zero pad row (neighbour index == N_POINTS hits it).
// Block: 256 threads = 32 b-lanes x 8; each block covers 32 consecutive n.
// Reads: lane b reads predict[b][n][0..2] (stride 600KB across lanes, but
// the 32-consecutive-n coverage per block gives full 64B-line use via L1).
// Writes: for fixed n, lanes write 384 contiguous bytes -> fully coalesced.
// ---------------------------------------------------------------------------
__global__ __launch_bounds__(256) void delta_transpose_kernel(
    const float* __restrict__ predict,
    const float* __restrict__ gt,
    float* __restrict__ delta)
{
    const int tx = threadIdx.x & 31;   // batch lane
    const int ty = threadIdx.x >> 5;   // 0..7
    const int n_base = blockIdx.x * 32;

#pragma unroll
    for (int i = 0; i < 4; ++i) {
        const int n = n_base + i * 8 + ty;
        if (n > N_POINTS) continue;          // tail of last block
        float dx = 0.f, dy = 0.f, dz = 0.f;
        if (n < N_POINTS) {
            const size_t off = (size_t)tx * (N_POINTS * 3) + (size_t)n * 3;
            dx = predict[off + 0] - gt[off + 0];
            dy = predict[off + 1] - gt[off + 1];
            dz = predict[off + 2] - gt[off + 2];
        }
        const size_t o = (size_t)n * ROW + tx * 3;
        delta[o + 0] = dx;
        delta[o + 1] = dy;
        delta[o + 2] = dz;
    }
}

// ---------------------------------------------------------------------------
// Kernel 2: per (b,n): diff = delta[n][b]*deg[n] - sum_d delta[nbr[n][d]][b];
// dist = |diff|; block-reduce; one atomicAdd per block (scaled by 1/BATCH).
// Block: 256 threads = 32 batches x 8 points. Neighbour indices + degrees
// staged in LDS (all 32 lanes of a half-wave read the same LDS word ->
// broadcast, conflict-free).
// ---------------------------------------------------------------------------
__global__ __launch_bounds__(256) void laplace_loss_kernel(
    const float* __restrict__ delta,
    const int*  __restrict__ neighbour,
    const int*  __restrict__ degrees,
    float* __restrict__ out)
{
    __shared__ int   s_nbr[8 * MAX_DEG];
    __shared__ float s_deg[8];
    __shared__ float s_part[4];

    const int t = threadIdx.x;
    const int n_base = blockIdx.x * 8;

    if (t < 8 * MAX_DEG)
        s_nbr[t] = neighbour[(size_t)n_base * MAX_DEG + t];
    if (t < 8)
        s_deg[t] = (float)degrees[n_base + t];
    __syncthreads();

    const int b  = t & 31;
    const int yn = t >> 5;
    const int n  = n_base + yn;          // grid is exact: n < N_POINTS always

    const float deg = s_deg[yn];
    const size_t coff = (size_t)n * ROW + b * 3;
    float ax = delta[coff + 0] * deg;
    float ay = delta[coff + 1] * deg;
    float az = delta[coff + 2] * deg;

#pragma unroll
    for (int d = 0; d < MAX_DEG; ++d) {
        const int idx = s_nbr[yn * MAX_DEG + d];
        const size_t o = (size_t)idx * ROW + b * 3;
        ax -= delta[o + 0];
        ay -= delta[o + 1];
        az -= delta[o + 2];
    }

    float dist = sqrtf(ax * ax + ay * ay + az * az);

    // wave (64-lane) shuffle reduction
#pragma unroll
    for (int o = 32; o > 0; o >>= 1)
        dist += __shfl_down(dist, o, 64);

    const int wave = t >> 6;
    if ((t & 63) == 0) s_part[wave] = dist;
    __syncthreads();

    if (t == 0) {
        const float total = s_part[0] + s_part[1] + s_part[2] + s_part[3];
        atomicAdd(out, total * (1.0f / BATCH));
    }
}

extern "C" void kernel_launch(void* const* d_in, const int* in_sizes, int n_in,
                              void* d_out, int out_size, void* d_ws, size_t ws_size,
                              hipStream_t stream)
{
    const float* predict   = (const float*)d_in[0];
    const float* gt        = (const float*)d_in[1];
    const int*   neighbour = (const int*)d_in[2];   // harness delivers integers as int32
    const int*   degrees   = (const int*)d_in[3];
    float* out = (float*)d_out;

    float* delta = (float*)d_ws;   // (N_POINTS+1) * 96 floats = 19.2 MB

    // d_out is re-poisoned before every timed launch; we accumulate atomically.
    hipMemsetAsync(out, 0, sizeof(float), stream);

    const int grid1 = (N_POINTS + 1 + 31) / 32;   // 1563 blocks, covers pad row
    delta_transpose_kernel<<<grid1, 256, 0, stream>>>(predict, gt, delta);

    const int grid2 = N_POINTS / 8;               // 6250 blocks, exact
    laplace_loss_kernel<<<grid2, 256, 0, stream>>>(delta, neighbour, degrees, out);
}

// Round 2
// 128.178 us; speedup vs baseline: 1.3916x; 1.3916x over previous
//
#include <hip/hip_runtime.h>
#include <math.h>

#define N_POINTS 50000
#define MAX_DEG 16
#define BATCH 32
#define ROW (BATCH * 3)      // 96 floats = 384 bytes per delta row
#define DELTA_FLOATS ((size_t)(N_POINTS + 1) * ROW)   // 4,800,096 floats

// ---------------------------------------------------------------------------
// Kernel 1: LDS-transposed delta computation.
// delta[n][b*3+c] = predict[b][n][c] - gt[b][n][c]; row N_POINTS zeroed (pad).
// Block: 256 threads; tile = 32 points x 32 batches x 3.
// Phase 1 (coalesced read): half-wave (32 lanes, fixed b) reads 384
//   contiguous bytes: lane = point n0+lane, 3 floats. Stored to LDS with
//   row stride 97 (pad) -> banks (lane + x) % 32, conflict-free.
// Phase 2 (coalesced write): half-wave (fixed n_local) reads
//   s[n_local][3*lane..] -> banks (3*lane+k)%32 distinct (gcd(3,32)=1),
//   writes 384 contiguous bytes of the delta row.
// ---------------------------------------------------------------------------
__global__ __launch_bounds__(256) void delta_transpose_kernel(
    const float* __restrict__ predict,
    const float* __restrict__ gt,
    float* __restrict__ delta)
{
    __shared__ float s[32][97];

    const int t    = threadIdx.x;
    const int lane = t & 31;
    const int ty   = t >> 5;          // 0..7
    const int n0   = blockIdx.x * 32;

    // Phase 1: load + diff + LDS store (b = iter*8 + ty, n = n0 + lane)
#pragma unroll
    for (int i = 0; i < 4; ++i) {
        const int b = i * 8 + ty;
        const int n = n0 + lane;
        float dx = 0.f, dy = 0.f, dz = 0.f;
        if (n < N_POINTS) {
            const size_t off = (size_t)b * (N_POINTS * 3) + (size_t)n * 3;
            dx = predict[off + 0] - gt[off + 0];
            dy = predict[off + 1] - gt[off + 1];
            dz = predict[off + 2] - gt[off + 2];
        }
        s[lane][b * 3 + 0] = dx;
        s[lane][b * 3 + 1] = dy;
        s[lane][b * 3 + 2] = dz;
    }
    __syncthreads();

    // Phase 2: LDS read + coalesced global store (n_local = iter*8 + ty)
#pragma unroll
    for (int i = 0; i < 4; ++i) {
        const int nl  = i * 8 + ty;
        const int row = n0 + nl;
        if (row <= N_POINTS) {
            const size_t o = (size_t)row * ROW + lane * 3;
            delta[o + 0] = s[nl][lane * 3 + 0];
            delta[o + 1] = s[nl][lane * 3 + 1];
            delta[o + 2] = s[nl][lane * 3 + 2];
        }
    }
}

// ---------------------------------------------------------------------------
// Kernel 2: gather + norm + block partial sum.
// Block: 256 threads = 32 batches x 8 points. All 16 neighbour gathers are
// buffered in registers FIRST (issues 17 independent dwordx3 loads back to
// back -> full memory-level parallelism), then accumulated.
// Per-block partial written to d_ws (no global atomics).
// ---------------------------------------------------------------------------
__global__ __launch_bounds__(256) void laplace_gather_kernel(
    const float* __restrict__ delta,
    const int*  __restrict__ neighbour,
    const int*  __restrict__ degrees,
    float* __restrict__ partial)
{
    __shared__ int   s_nbr[8 * MAX_DEG];
    __shared__ float s_deg[8];
    __shared__ float s_part[4];

    const int t = threadIdx.x;
    const int n_base = blockIdx.x * 8;

    if (t < 8 * MAX_DEG)
        s_nbr[t] = neighbour[(size_t)n_base * MAX_DEG + t];
    if (t < 8)
        s_deg[t] = (float)degrees[n_base + t];
    __syncthreads();

    const int b  = t & 31;
    const int yn = t >> 5;
    const int n  = n_base + yn;       // grid exact: n < N_POINTS

    // Issue all 17 gathers before any accumulation (register-buffered).
    const float* __restrict__ rc = delta + (size_t)n * ROW + b * 3;
    float cx = rc[0], cy = rc[1], cz = rc[2];

    float vx[MAX_DEG], vy[MAX_DEG], vz[MAX_DEG];
#pragma unroll
    for (int d = 0; d < MAX_DEG; ++d) {
        const int idx = s_nbr[yn * MAX_DEG + d];
        const float* __restrict__ r = delta + (size_t)idx * ROW + b * 3;
        vx[d] = r[0];
        vy[d] = r[1];
        vz[d] = r[2];
    }

    // Balanced accumulation (short dep chains).
    float sx = 0.f, sy = 0.f, sz = 0.f;
#pragma unroll
    for (int d = 0; d < MAX_DEG; ++d) {
        sx += vx[d]; sy += vy[d]; sz += vz[d];
    }

    const float deg = s_deg[yn];
    const float ax = fmaf(cx, deg, -sx);
    const float ay = fmaf(cy, deg, -sy);
    const float az = fmaf(cz, deg, -sz);

    float dist = sqrtf(ax * ax + ay * ay + az * az);

    // 64-lane wave reduction, then 4-wave LDS reduction.
#pragma unroll
    for (int o = 32; o > 0; o >>= 1)
        dist += __shfl_down(dist, o, 64);

    if ((t & 63) == 0) s_part[t >> 6] = dist;
    __syncthreads();

    if (t == 0)
        partial[blockIdx.x] = s_part[0] + s_part[1] + s_part[2] + s_part[3];
}

// ---------------------------------------------------------------------------
// Kernel 3: reduce 6250 block partials -> scalar loss (mean over batch).
// ---------------------------------------------------------------------------
__global__ __launch_bounds__(256) void final_reduce_kernel(
    const float* __restrict__ partial, float* __restrict__ out, int nparts)
{
    __shared__ float s_part[4];
    const int t = threadIdx.x;

    float acc = 0.f;
    for (int i = t; i < nparts; i += 256)
        acc += partial[i];

#pragma unroll
    for (int o = 32; o > 0; o >>= 1)
        acc += __shfl_down(acc, o, 64);

    if ((t & 63) == 0) s_part[t >> 6] = acc;
    __syncthreads();

    if (t == 0)
        out[0] = (s_part[0] + s_part[1] + s_part[2] + s_part[3]) * (1.0f / BATCH);
}

extern "C" void kernel_launch(void* const* d_in, const int* in_sizes, int n_in,
                              void* d_out, int out_size, void* d_ws, size_t ws_size,
                              hipStream_t stream)
{
    const float* predict   = (const float*)d_in[0];
    const float* gt        = (const float*)d_in[1];
    const int*   neighbour = (const int*)d_in[2];
    const int*   degrees   = (const int*)d_in[3];
    float* out = (float*)d_out;

    float* delta   = (float*)d_ws;                 // 19.2 MB
    float* partial = delta + DELTA_FLOATS;         // +25 KB

    const int grid1 = (N_POINTS + 1 + 31) / 32;    // 1563 blocks (covers pad row)
    delta_transpose_kernel<<<grid1, 256, 0, stream>>>(predict, gt, delta);

    const int grid2 = N_POINTS / 8;                // 6250 blocks, exact
    laplace_gather_kernel<<<grid2, 256, 0, stream>>>(delta, neighbour, degrees, partial);

    final_reduce_kernel<<<1, 256, 0, stream>>>(partial, out, grid2);
}

// Round 3
// 112.493 us; speedup vs baseline: 1.5857x; 1.1394x over previous
//
#include <hip/hip_runtime.h>
#include <hip/hip_fp16.h>
#include <math.h>

#define N_POINTS 50000
#define MAX_DEG 16
#define BATCH 32

// delta layout: [N_POINTS+1][BATCH] of H4 (x,y,z,0 packed as 2x half2, 8 B).
// Row = 256 B (4 cache lines). Row N_POINTS is the zero pad row.
struct alignas(8) H4 { __half2 a, b; };   // a=(x,y), b=(z,0)
#define DELTA_ELEMS ((size_t)(N_POINTS + 1) * BATCH)

// ---------------------------------------------------------------------------
// Kernel 1: delta = fp16(predict - gt), transposed [b][n][3] -> [n][b][4].
// Block 256, tile = 32 points x 32 batches.
// Phase 1: float4-vectorized coalesced reads (24 float4 per b-row, 8 threads
//   x 3 each), diff, pack to half2, store to LDS rows of 100 halfs (200 B
//   stride -> phase-2 bank aliasing is 2-way max = free).
// Phase 2: lane b packs 3 halfs -> H4, writes 256 B contiguous per row
//   (global_store_dwordx2, fully coalesced).
// ---------------------------------------------------------------------------
__global__ __launch_bounds__(256) void delta_transpose_kernel(
    const float* __restrict__ predict,
    const float* __restrict__ gt,
    H4* __restrict__ delta)
{
    __shared__ __half s_h[32][100];   // 32 b-rows x 96 halfs (+4 pad)

    const int t  = threadIdx.x;
    const int n0 = blockIdx.x * 32;

    // Phase 1: b = t>>3, q = t&7; float4 j = k*8+q, k=0..2 (24 f4 per row)
    {
        const int b = t >> 3;
        const int q = t & 7;
        const size_t base_f4 = ((size_t)b * (N_POINTS * 3) + (size_t)n0 * 3) >> 2;
        const float4* __restrict__ p4 = (const float4*)predict;
        const float4* __restrict__ g4 = (const float4*)gt;
        const int valid_f4 = ((N_POINTS - n0) * 3) >> 2;   // floats valid / 4
        __half2* row2 = (__half2*)&s_h[b][0];
#pragma unroll
        for (int k = 0; k < 3; ++k) {
            const int j = k * 8 + q;
            float4 d = make_float4(0.f, 0.f, 0.f, 0.f);
            if (j < valid_f4) {
                const float4 p = p4[base_f4 + j];
                const float4 g = g4[base_f4 + j];
                d.x = p.x - g.x; d.y = p.y - g.y;
                d.z = p.z - g.z; d.w = p.w - g.w;
            }
            row2[j * 2 + 0] = __floats2half2_rn(d.x, d.y);
            row2[j * 2 + 1] = __floats2half2_rn(d.z, d.w);
        }
    }
    __syncthreads();

    // Phase 2: nl = i*8 + (t>>5), b = t&31; write H4 row-major coalesced.
    {
        const int b = t & 31;
#pragma unroll
        for (int i = 0; i < 4; ++i) {
            const int nl = i * 8 + (t >> 5);
            const int n  = n0 + nl;
            if (n <= N_POINTS) {
                const __half h0 = s_h[b][nl * 3 + 0];
                const __half h1 = s_h[b][nl * 3 + 1];
                const __half h2 = s_h[b][nl * 3 + 2];
                H4 val;
                val.a = __halves2half2(h0, h1);
                val.b = __halves2half2(h2, __float2half(0.f));
                delta[(size_t)n * BATCH + b] = val;
            }
        }
    }
}

// ---------------------------------------------------------------------------
// Kernel 2: per (b,n): diff = delta[n][b]*deg[n] - sum_d delta[nbr[n][d]][b].
// Block 256 = 8 points x 32 batches. Each gather row = one 8-B dwordx2 per
// lane, 256 B contiguous per half-wave. All 17 loads register-buffered
// (full MLP), then unpacked to fp32 and accumulated.
// ---------------------------------------------------------------------------
__global__ __launch_bounds__(256) void laplace_gather_kernel(
    const H4* __restrict__ delta,
    const int*  __restrict__ neighbour,
    const int*  __restrict__ degrees,
    float* __restrict__ partial)
{
    __shared__ int   s_nbr[8 * MAX_DEG];
    __shared__ float s_deg[8];
    __shared__ float s_part[4];

    const int t = threadIdx.x;
    const int n_base = blockIdx.x * 8;

    if (t < 8 * MAX_DEG)
        s_nbr[t] = neighbour[(size_t)n_base * MAX_DEG + t];
    if (t < 8)
        s_deg[t] = (float)degrees[n_base + t];
    __syncthreads();

    const int b  = t & 31;
    const int yn = t >> 5;
    const int n  = n_base + yn;            // grid exact: n < N_POINTS

    // Issue all 17 independent 8-B gathers before any unpacking.
    const H4 c = delta[(size_t)n * BATCH + b];
    H4 v[MAX_DEG];
#pragma unroll
    for (int d = 0; d < MAX_DEG; ++d) {
        const int idx = s_nbr[yn * MAX_DEG + d];
        v[d] = delta[(size_t)idx * BATCH + b];
    }

    float sx = 0.f, sy = 0.f, sz = 0.f;
#pragma unroll
    for (int d = 0; d < MAX_DEG; ++d) {
        const float2 xy = __half22float2(v[d].a);
        sx += xy.x;
        sy += xy.y;
        sz += __low2float(v[d].b);
    }

    const float deg = s_deg[yn];
    const float2 cxy = __half22float2(c.a);
    const float  cz  = __low2float(c.b);
    const float ax = fmaf(cxy.x, deg, -sx);
    const float ay = fmaf(cxy.y, deg, -sy);
    const float az = fmaf(cz,    deg, -sz);

    float dist = sqrtf(ax * ax + ay * ay + az * az);

#pragma unroll
    for (int o = 32; o > 0; o >>= 1)
        dist += __shfl_down(dist, o, 64);

    if ((t & 63) == 0) s_part[t >> 6] = dist;
    __syncthreads();

    if (t == 0)
        partial[blockIdx.x] = s_part[0] + s_part[1] + s_part[2] + s_part[3];
}

// ---------------------------------------------------------------------------
// Kernel 3: reduce 6250 block partials -> scalar loss (mean over batch).
// ---------------------------------------------------------------------------
__global__ __launch_bounds__(256) void final_reduce_kernel(
    const float* __restrict__ partial, float* __restrict__ out, int nparts)
{
    __shared__ float s_part[4];
    const int t = threadIdx.x;

    float acc = 0.f;
#pragma unroll 4
    for (int i = t; i < nparts; i += 256)
        acc += partial[i];

#pragma unroll
    for (int o = 32; o > 0; o >>= 1)
        acc += __shfl_down(acc, o, 64);

    if ((t & 63) == 0) s_part[t >> 6] = acc;
    __syncthreads();

    if (t == 0)
        out[0] = (s_part[0] + s_part[1] + s_part[2] + s_part[3]) * (1.0f / BATCH);
}

extern "C" void kernel_launch(void* const* d_in, const int* in_sizes, int n_in,
                              void* d_out, int out_size, void* d_ws, size_t ws_size,
                              hipStream_t stream)
{
    const float* predict   = (const float*)d_in[0];
    const float* gt        = (const float*)d_in[1];
    const int*   neighbour = (const int*)d_in[2];
    const int*   degrees   = (const int*)d_in[3];
    float* out = (float*)d_out;

    H4*    delta   = (H4*)d_ws;                      // 12.8 MB
    float* partial = (float*)(delta + DELTA_ELEMS);  // +25 KB

    const int grid1 = (N_POINTS + 1 + 31) / 32;      // 1563 blocks (covers pad row)
    delta_transpose_kernel<<<grid1, 256, 0, stream>>>(predict, gt, delta);

    const int grid2 = N_POINTS / 8;                  // 6250 blocks, exact
    laplace_gather_kernel<<<grid2, 256, 0, stream>>>(delta, neighbour, degrees, partial);

    final_reduce_kernel<<<1, 256, 0, stream>>>(partial, out, grid2);
}

// Round 4
// 110.982 us; speedup vs baseline: 1.6073x; 1.0136x over previous
//
#include <hip/hip_runtime.h>
#include <hip/hip_fp16.h>
#include <math.h>

#define N_POINTS 50000
#define MAX_DEG 16
#define BATCH 32
#define NGROUP 4                         // 4 batch groups of 8
#define GROUP_B 8                        // batches per group; row = 64 B
#define SLAB ((size_t)(N_POINTS + 1))    // rows per group slab (incl. zero pad row)

// delta layout: [g][n][b_local] of H4 (x,y,z,0 as 2x half2, 8 B each).
// One (g,n) row = 8 * 8 B = 64 B = exactly one cache line.
// Per-group slab = 50001 * 64 B = 3.2 MB  ->  fits one XCD's 4 MB L2.
struct alignas(8) H4 { __half2 a, b; };  // a=(x,y), b=(z,0)
#define DELTA_ELEMS ((size_t)NGROUP * SLAB * GROUP_B)

// ---------------------------------------------------------------------------
// Kernel 1: delta = fp16(predict - gt), [b][n][3] -> [g][n][bl][4].
// Block 256, tile = 32 points x 32 batches. Phase 1: float4 coalesced reads,
// pack half2 into LDS (row stride 200 B -> worst 2-way bank alias = free).
// Phase 2: each half-wave writes one point-row: 4 groups x 64 B segments.
// ---------------------------------------------------------------------------
__global__ __launch_bounds__(256) void delta_transpose_kernel(
    const float* __restrict__ predict,
    const float* __restrict__ gt,
    H4* __restrict__ delta)
{
    __shared__ __half s_h[32][100];   // [batch][point*3], +4 pad halfs

    const int t  = threadIdx.x;
    const int n0 = blockIdx.x * 32;

    // Phase 1: b = t>>3, q = t&7; float4 j = k*8+q (24 float4 per b-row)
    {
        const int b = t >> 3;
        const int q = t & 7;
        const size_t base_f4 = ((size_t)b * (N_POINTS * 3) + (size_t)n0 * 3) >> 2;
        const float4* __restrict__ p4 = (const float4*)predict;
        const float4* __restrict__ g4 = (const float4*)gt;
        const int valid_f4 = ((N_POINTS - n0) * 3) >> 2;
        __half2* row2 = (__half2*)&s_h[b][0];
#pragma unroll
        for (int k = 0; k < 3; ++k) {
            const int j = k * 8 + q;
            float4 d = make_float4(0.f, 0.f, 0.f, 0.f);
            if (j < valid_f4) {
                const float4 p = p4[base_f4 + j];
                const float4 g = g4[base_f4 + j];
                d.x = p.x - g.x; d.y = p.y - g.y;
                d.z = p.z - g.z; d.w = p.w - g.w;
            }
            row2[j * 2 + 0] = __floats2half2_rn(d.x, d.y);
            row2[j * 2 + 1] = __floats2half2_rn(d.z, d.w);
        }
    }
    __syncthreads();

    // Phase 2: nl = i*8 + (t>>5); lane b = t&31 -> slab g = b>>3, lane bl = b&7
    {
        const int b  = t & 31;
        const int g  = b >> 3;
        const int bl = b & 7;
#pragma unroll
        for (int i = 0; i < 4; ++i) {
            const int nl = i * 8 + (t >> 5);
            const int n  = n0 + nl;
            if (n <= N_POINTS) {
                H4 val;
                val.a = __halves2half2(s_h[b][nl * 3 + 0], s_h[b][nl * 3 + 1]);
                val.b = __halves2half2(s_h[b][nl * 3 + 2], __ushort_as_half(0));
                delta[((size_t)g * SLAB + n) * GROUP_B + bl] = val;
            }
        }
    }
}

// ---------------------------------------------------------------------------
// Kernel 2: gather + norm + block partial sum, XCD-sharded by batch group.
// g = blockIdx & 3 is constant per XCD under round-robin dispatch (XCD =
// blockIdx % 8), so each XCD's L2 only ever caches its own 3.2 MB slab.
// Block 256 = 32 points x 8 batch-lanes; wave gather = 8 distinct 64-B lines.
// All 17 loads register-buffered for full MLP.
// ---------------------------------------------------------------------------
__global__ __launch_bounds__(256) void laplace_gather_kernel(
    const H4* __restrict__ delta,
    const int*  __restrict__ neighbour,
    const int*  __restrict__ degrees,
    float* __restrict__ partial)
{
    __shared__ int   s_nbr[32 * 17];   // stride 17 (coprime 32) -> no conflicts
    __shared__ float s_deg[32];
    __shared__ float s_part[4];

    const int t    = threadIdx.x;
    const int g    = blockIdx.x & 3;          // batch group == f(XCD)
    const int nb   = (blockIdx.x >> 2) * 32;  // point tile base

    // Stage 32 points x 16 indices (2 per thread) + 32 degrees.
#pragma unroll
    for (int r = 0; r < 2; ++r) {
        const int i  = t + r * 256;           // [0,512)
        const int pt = i >> 4, d = i & 15;
        const int n  = nb + pt;
        s_nbr[pt * 17 + d] = (n < N_POINTS) ? neighbour[(size_t)n * MAX_DEG + d]
                                            : N_POINTS;   // pad row
    }
    if (t < 32) {
        const int n = nb + t;
        s_deg[t] = (n < N_POINTS) ? (float)degrees[n] : 0.f;
    }
    __syncthreads();

    const int pt = t >> 3;
    const int bl = t & 7;
    const int n  = nb + pt;
    const int nn = (n < N_POINTS) ? n : N_POINTS;   // invalid -> zero pad row
    const H4* __restrict__ slab = delta + (size_t)g * SLAB * GROUP_B;

    // Issue all 17 independent 8-B gathers before any unpacking.
    const H4 c = slab[(size_t)nn * GROUP_B + bl];
    H4 v[MAX_DEG];
#pragma unroll
    for (int d = 0; d < MAX_DEG; ++d) {
        const int idx = s_nbr[pt * 17 + d];
        v[d] = slab[(size_t)idx * GROUP_B + bl];
    }

    float sx = 0.f, sy = 0.f, sz = 0.f;
#pragma unroll
    for (int d = 0; d < MAX_DEG; ++d) {
        const float2 xy = __half22float2(v[d].a);
        sx += xy.x;
        sy += xy.y;
        sz += __low2float(v[d].b);
    }

    const float deg = s_deg[pt];
    const float2 cxy = __half22float2(c.a);
    const float ax = fmaf(cxy.x, deg, -sx);
    const float ay = fmaf(cxy.y, deg, -sy);
    const float az = fmaf(__low2float(c.b), deg, -sz);

    float dist = (n < N_POINTS) ? sqrtf(ax * ax + ay * ay + az * az) : 0.f;

#pragma unroll
    for (int o = 32; o > 0; o >>= 1)
        dist += __shfl_down(dist, o, 64);

    if ((t & 63) == 0) s_part[t >> 6] = dist;
    __syncthreads();

    if (t == 0)
        partial[blockIdx.x] = s_part[0] + s_part[1] + s_part[2] + s_part[3];
}

// ---------------------------------------------------------------------------
// Kernel 3: reduce block partials -> scalar loss (mean over batch).
// ---------------------------------------------------------------------------
__global__ __launch_bounds__(256) void final_reduce_kernel(
    const float* __restrict__ partial, float* __restrict__ out, int nparts)
{
    __shared__ float s_part[4];
    const int t = threadIdx.x;

    float acc = 0.f;
#pragma unroll 4
    for (int i = t; i < nparts; i += 256)
        acc += partial[i];

#pragma unroll
    for (int o = 32; o > 0; o >>= 1)
        acc += __shfl_down(acc, o, 64);

    if ((t & 63) == 0) s_part[t >> 6] = acc;
    __syncthreads();

    if (t == 0)
        out[0] = (s_part[0] + s_part[1] + s_part[2] + s_part[3]) * (1.0f / BATCH);
}

extern "C" void kernel_launch(void* const* d_in, const int* in_sizes, int n_in,
                              void* d_out, int out_size, void* d_ws, size_t ws_size,
                              hipStream_t stream)
{
    const float* predict   = (const float*)d_in[0];
    const float* gt        = (const float*)d_in[1];
    const int*   neighbour = (const int*)d_in[2];
    const int*   degrees   = (const int*)d_in[3];
    float* out = (float*)d_out;

    H4*    delta   = (H4*)d_ws;                      // 12.8 MB (4 slabs x 3.2 MB)
    float* partial = (float*)(delta + DELTA_ELEMS);  // +25 KB

    const int tiles = (N_POINTS + 1 + 31) / 32;      // 1563 point tiles
    delta_transpose_kernel<<<tiles, 256, 0, stream>>>(predict, gt, delta);

    const int grid2 = tiles * NGROUP;                // 6252 blocks
    laplace_gather_kernel<<<grid2, 256, 0, stream>>>(delta, neighbour, degrees, partial);

    final_reduce_kernel<<<1, 256, 0, stream>>>(partial, out, grid2);
}